// Round 1
// baseline (293.180 us; speedup 1.0000x reference)
//
#include <hip/hip_runtime.h>
#include <hip/hip_fp16.h>

#define DIM 64
#define NEG_SLOPE 0.01f
#define TILE 2048        // scan1 tile: 256 thr x 8 elems

typedef unsigned u32;
typedef unsigned long long u64;

// ---------------------------------------------------------------------------
// Round 9: replace the bucket-sort CSR build (hist-matrix / scan-M / place /
// bucket) with a direct atomic-cursor CSR build:
//   deg[v]  = global atomicAdd over p[] (deg[v] == #occurrences of v in
//             p[0..2E), since symmetrization uses both rows as dst)
//   row_ptr = exclusive scan of deg (3-kernel scan over N=200K)
//   colw    placed directly: slot = atomicAdd(&cur[dst], 1)
// Deletes places[] (9.6MB W + 19.2MB R) and k_bucket (391-block,
// occupancy-starved, two LDS-atomic passes). Convs byte-identical to R8
// to isolate the build delta.
// ---------------------------------------------------------------------------

__global__ void k_zero(u32* __restrict__ deg, int N) {
    int i = (blockIdx.x * 256 + threadIdx.x) * 4;
    if (i + 3 < N) {
        *(uint4*)(deg + i) = make_uint4(0u, 0u, 0u, 0u);
    } else {
        for (int k = i; k < N; k++) deg[k] = 0u;
    }
}

__global__ void k_norm_deg(const float* __restrict__ emb,
                           __half* __restrict__ x0h,
                           const int* __restrict__ p,
                           u32* __restrict__ deg,
                           int N, int E, int rb) {
    if ((int)blockIdx.x < rb) {
        // L2-normalize one row per 16 lanes, 4 rows/wave, float4/lane
        int lane = threadIdx.x & 63;
        int row  = blockIdx.x * 16 + (threadIdx.x >> 6) * 4 + (lane >> 4);
        int l16  = lane & 15;
        if (row >= N) return;
        float4 v = *(const float4*)(emb + (size_t)row * DIM + l16 * 4);
        float s = v.x * v.x + v.y * v.y + v.z * v.z + v.w * v.w;
        #pragma unroll
        for (int m = 1; m < 16; m <<= 1) s += __shfl_xor(s, m, 64);
        float inv = 1.0f / fmaxf(sqrtf(s), 1e-12f);
        union { uint2 u; __half2 h[2]; } pk;
        pk.h[0] = __floats2half2_rn(v.x * inv, v.y * inv);
        pk.h[1] = __floats2half2_rn(v.z * inv, v.w * inv);
        *(uint2*)(x0h + (size_t)row * DIM + l16 * 4) = pk.u;
    } else {
        // degree histogram: one int4 of p per thread, 4 global atomics.
        // ~6 edges/node avg -> negligible contention; L2-resident (800KB).
        int i = ((blockIdx.x - rb) * 256 + threadIdx.x) * 4;
        if (i + 3 < 2 * E) {
            int4 v = *(const int4*)(p + i);
            atomicAdd(&deg[(u32)v.x], 1u);
            atomicAdd(&deg[(u32)v.y], 1u);
            atomicAdd(&deg[(u32)v.z], 1u);
            atomicAdd(&deg[(u32)v.w], 1u);
        } else {
            for (int k = i; k < 2 * E; k++) atomicAdd(&deg[(u32)p[k]], 1u);
        }
    }
}

__global__ void k_scan1(const u32* __restrict__ in, u32* __restrict__ out,
                        u32* __restrict__ bsum, int M) {
    __shared__ u32 sdata[256];
    int t = threadIdx.x;
    int base = blockIdx.x * TILE + t * 8;
    u32 v[8]; u32 tsum = 0;
    #pragma unroll
    for (int k = 0; k < 8; k++) {
        int i = base + k;
        v[k] = (i < M) ? in[i] : 0u;
        tsum += v[k];
    }
    sdata[t] = tsum;
    __syncthreads();
    for (int off = 1; off < 256; off <<= 1) {
        u32 x = (t >= off) ? sdata[t - off] : 0u;
        __syncthreads();
        sdata[t] += x;
        __syncthreads();
    }
    u32 run = sdata[t] - tsum;
    if (t == 255) bsum[blockIdx.x] = sdata[255];
    #pragma unroll
    for (int k = 0; k < 8; k++) {
        int i = base + k;
        if (i < M) out[i] = run;
        run += v[k];
    }
}

__global__ void k_scan2(u32* __restrict__ bsum, int nb) {
    __shared__ u32 sdata[256];
    int t = threadIdx.x;
    u32 v = (t < nb) ? bsum[t] : 0u;
    sdata[t] = v;
    __syncthreads();
    for (int off = 1; off < 256; off <<= 1) {
        u32 x = (t >= off) ? sdata[t - off] : 0u;
        __syncthreads();
        sdata[t] += x;
        __syncthreads();
    }
    if (t < nb) bsum[t] = sdata[t] - v;
}

// fold block offsets; emit row_ptr AND the atomic cursor copy in one pass
__global__ void k_scanfix(const u32* __restrict__ mscan,
                          const u32* __restrict__ bsum,
                          u32* __restrict__ row_ptr,
                          u32* __restrict__ cur, int N, int E2) {
    int i = blockIdx.x * 256 + threadIdx.x;
    if (i == 0) row_ptr[N] = (u32)E2;
    if (i >= N) return;
    u32 v = mscan[i] + bsum[i >> 11];
    row_ptr[i] = v;
    cur[i] = v;
}

__global__ void k_place2(const int* __restrict__ p, const float* __restrict__ w,
                         u32* __restrict__ cur, u32* __restrict__ colw, int E) {
    int e = blockIdx.x * 256 + threadIdx.x;
    if (e >= 2 * E) return;
    int src = p[e];
    int dst = (e < E) ? p[e + E] : p[e - E];
    u32 w14 = (u32)(w[e] * 16384.0f + 0.5f);
    if (w14 > 16383u) w14 = 16383u;
    u32 slot = atomicAdd(&cur[dst], 1u);
    colw[slot] = ((u32)src << 14) | w14;
}

// --- conv: 8 rows/wave, 8 lanes/row, lane covers dims [sub*8, sub*8+8) ----

__device__ __forceinline__ void gather8(const __half* __restrict__ x,
                                        const u32* __restrict__ colw,
                                        u32 s, u32 e, int g, int sub,
                                        float acc[8]) {
    for (u32 base = s; base < e; base += 8) {
        u32 u = 0;
        if (base + (u32)sub < e) u = colw[base + sub];
        int   cx = (int)(u >> 14);
        float cy = (float)(u & 16383u) * (1.0f / 16384.0f);
        #pragma unroll
        for (int j = 0; j < 8; j++) {
            int   sj = __shfl(cx, (g << 3) | j, 64);
            float wj = __shfl(cy, (g << 3) | j, 64);
            uint4 q = *(const uint4*)(x + (size_t)sj * DIM + sub * 8);
            const __half2* hp = (const __half2*)&q;
            #pragma unroll
            for (int k = 0; k < 4; k++) {
                float2 f = __half22float2(hp[k]);
                acc[2 * k]     += f.x * wj;
                acc[2 * k + 1] += f.y * wj;
            }
        }
    }
}

__global__ void k_conv1(const __half* __restrict__ x0h,
                        const u32* __restrict__ row_ptr,
                        const u32* __restrict__ colw,
                        __half* __restrict__ x1h, int N) {
    int wave = (blockIdx.x * 256 + threadIdx.x) >> 6;
    int g    = (threadIdx.x >> 3) & 7;
    int sub  = threadIdx.x & 7;
    int row  = wave * 8 + g;
    if (row >= N) return;
    u32 s = row_ptr[row], e = row_ptr[row + 1];
    float acc[8] = {0, 0, 0, 0, 0, 0, 0, 0};
    gather8(x0h, colw, s, e, g, sub, acc);
    float rdeno = 1.0f / fmaxf((float)(e - s), 1.0f);
    __half2 hv[4];
    #pragma unroll
    for (int k = 0; k < 4; k++) {
        float v0 = acc[2 * k] * rdeno;
        float v1 = acc[2 * k + 1] * rdeno;
        v0 = (v0 >= 0.0f) ? v0 : NEG_SLOPE * v0;
        v1 = (v1 >= 0.0f) ? v1 : NEG_SLOPE * v1;
        hv[k] = __floats2half2_rn(v0, v1);
    }
    *(uint4*)(x1h + (size_t)row * DIM + sub * 8) = *(const uint4*)hv;
}

__global__ void k_conv2(const __half* __restrict__ x0h,
                        const __half* __restrict__ x1h,
                        const u32* __restrict__ row_ptr,
                        const u32* __restrict__ colw,
                        float* __restrict__ out, int N) {
    int wave = (blockIdx.x * 256 + threadIdx.x) >> 6;
    int g    = (threadIdx.x >> 3) & 7;
    int sub  = threadIdx.x & 7;
    int row  = wave * 8 + g;
    if (row >= N) return;
    u32 s = row_ptr[row], e = row_ptr[row + 1];
    float acc[8] = {0, 0, 0, 0, 0, 0, 0, 0};
    gather8(x1h, colw, s, e, g, sub, acc);
    float rdeno = 1.0f / fmaxf((float)(e - s), 1.0f);
    uint4 q0 = *(const uint4*)(x0h + (size_t)row * DIM + sub * 8);
    uint4 q1 = *(const uint4*)(x1h + (size_t)row * DIM + sub * 8);
    const __half2* h0 = (const __half2*)&q0;
    const __half2* h1 = (const __half2*)&q1;
    float r[8];
    #pragma unroll
    for (int k = 0; k < 4; k++) {
        float2 a = __half22float2(h0[k]);
        float2 b = __half22float2(h1[k]);
        float x2a = acc[2 * k] * rdeno;
        float x2b = acc[2 * k + 1] * rdeno;
        x2a = (x2a >= 0.0f) ? x2a : NEG_SLOPE * x2a;
        x2b = (x2b >= 0.0f) ? x2b : NEG_SLOPE * x2b;
        r[2 * k]     = a.x + b.x + x2a;
        r[2 * k + 1] = a.y + b.y + x2b;
    }
    float* op = out + (size_t)row * DIM + sub * 8;
    *(float4*)(op)     = make_float4(r[0], r[1], r[2], r[3]);
    *(float4*)(op + 4) = make_float4(r[4], r[5], r[6], r[7]);
}

static inline size_t align16(size_t x) { return (x + 15) & ~(size_t)15; }

extern "C" void kernel_launch(void* const* d_in, const int* in_sizes, int n_in,
                              void* d_out, int out_size, void* d_ws, size_t ws_size,
                              hipStream_t stream) {
    const int N = in_sizes[0] / DIM;      // 200000
    const int E = in_sizes[1] / 2;        // 600000

    const float* emb = (const float*)d_in[0];
    const int*   ei  = (const int*)d_in[1];
    const float* w   = (const float*)d_in[2];
    float*       out = (float*)d_out;

    const int rb   = (N + 15) / 16;               // 12500 norm blocks
    const int degb = (2 * E + 1023) / 1024;       // 1172 deg blocks (int4/thr)
    const int nb1  = (N + TILE - 1) / TILE;       // 98 scan blocks
    const int zb   = (N + 1023) / 1024;           // 196 zero blocks
    const int pb   = (2 * E + 255) / 256;         // 4688 place blocks
    const int cvb  = (N + 31) / 32;               // conv blocks: 32 rows/block

    char* ws = (char*)d_ws;
    size_t off = 0;
    __half* x0h    = (__half*)(ws + off); off += align16((size_t)N * DIM * 2);
    __half* x1h    = (__half*)(ws + off); off += align16((size_t)N * DIM * 2);
    u32*    colw   = (u32*)(ws + off);    off += align16((size_t)2 * E * 4);
    u32*    deg    = (u32*)(ws + off);    off += align16((size_t)N * 4);
    u32*    mscan  = (u32*)(ws + off);    off += align16((size_t)N * 4);
    u32*    row_ptr= (u32*)(ws + off);    off += align16((size_t)(N + 1) * 4);
    u32*    cur    = (u32*)(ws + off);    off += align16((size_t)N * 4);
    u32*    bsum   = (u32*)(ws + off);    off += align16(256 * 4);

    k_zero    <<<zb, 256, 0, stream>>>(deg, N);
    k_norm_deg<<<rb + degb, 256, 0, stream>>>(emb, x0h, ei, deg, N, E, rb);
    k_scan1   <<<nb1, 256, 0, stream>>>(deg, mscan, bsum, N);
    k_scan2   <<<1, 256, 0, stream>>>(bsum, nb1);
    k_scanfix <<<(N + 255) / 256, 256, 0, stream>>>(mscan, bsum, row_ptr, cur, N, 2 * E);
    k_place2  <<<pb, 256, 0, stream>>>(ei, w, cur, colw, E);

    k_conv1<<<cvb, 256, 0, stream>>>(x0h, row_ptr, colw, x1h, N);
    k_conv2<<<cvb, 256, 0, stream>>>(x0h, x1h, row_ptr, colw, out, N);
}

// Round 2
// 250.274 us; speedup vs baseline: 1.1714x; 1.1714x over previous
//
#include <hip/hip_runtime.h>
#include <hip/hip_fp16.h>

#define DIM 64
#define NEG_SLOPE 0.01f
#define BKT 256          // nodes per bucket (smaller -> 782 blocks, 3/CU)
#define TILE 2048        // edges per block in hist/place (scan tile too)

typedef unsigned u32;
typedef unsigned long long u64;

// ---------------------------------------------------------------------------
// Round 10: R9's direct atomic placement caused 17x write amplification
// (84MB WRITE_SIZE for 4.8MB of colw: random 4B stores across 8 XCDs dirty
// a full line each). Revert to the two-pass radix build (writes confined to
// per-block per-bin contiguous runs) with fixes:
//   - BKT 512->256: k_bucket 391->782 blocks (1.5->3 per CU)
//   - places u64 -> pay u32 + loc8 u8: bucket-phase reads 38.4->14.4MB,
//     place writes 9.6->6MB
//   - k_scan2 folded into k_scanfix (each block rescans 224 bsums in LDS):
//     removes the 1-block serialization + one launch
//   - conv: inner j-loop bounded by valid count (drop dummy row-0 gathers)
// ---------------------------------------------------------------------------

__global__ void k_norm_hist(const float* __restrict__ emb,
                            __half* __restrict__ x0h,
                            const int* __restrict__ p,
                            u32* __restrict__ mat,
                            int N, int E, int rb, int B, int nblkE) {
    if ((int)blockIdx.x < rb) {
        int lane = threadIdx.x & 63;
        int row  = blockIdx.x * 16 + (threadIdx.x >> 6) * 4 + (lane >> 4);
        int l16  = lane & 15;
        if (row >= N) return;
        float4 v = *(const float4*)(emb + (size_t)row * DIM + l16 * 4);
        float s = v.x * v.x + v.y * v.y + v.z * v.z + v.w * v.w;
        #pragma unroll
        for (int m = 1; m < 16; m <<= 1) s += __shfl_xor(s, m, 64);
        float inv = 1.0f / fmaxf(sqrtf(s), 1e-12f);
        union { uint2 u; __half2 h[2]; } pk;
        pk.h[0] = __floats2half2_rn(v.x * inv, v.y * inv);
        pk.h[1] = __floats2half2_rn(v.z * inv, v.w * inv);
        *(uint2*)(x0h + (size_t)row * DIM + l16 * 4) = pk.u;
    } else {
        __shared__ u32 hist[800];           // B = 782 bins
        int blk = blockIdx.x - rb;
        int t = threadIdx.x;
        for (int i = t; i < B; i += 256) hist[i] = 0;
        __syncthreads();
        int base = blk * TILE;
        #pragma unroll
        for (int k = 0; k < TILE / 256; k++) {
            int e = base + k * 256 + t;
            if (e < 2 * E) {
                int dst = (e < E) ? p[e + E] : p[e - E];
                atomicAdd(&hist[(u32)dst >> 8], 1u);
            }
        }
        __syncthreads();
        for (int i = t; i < B; i += 256) mat[(size_t)i * nblkE + blk] = hist[i];
    }
}

__global__ void k_scan1(const u32* __restrict__ in, u32* __restrict__ out,
                        u32* __restrict__ bsum, int M) {
    __shared__ u32 sdata[256];
    int t = threadIdx.x;
    int base = blockIdx.x * TILE + t * 8;
    u32 v[8]; u32 tsum = 0;
    #pragma unroll
    for (int k = 0; k < 8; k++) {
        int i = base + k;
        v[k] = (i < M) ? in[i] : 0u;
        tsum += v[k];
    }
    sdata[t] = tsum;
    __syncthreads();
    for (int off = 1; off < 256; off <<= 1) {
        u32 x = (t >= off) ? sdata[t - off] : 0u;
        __syncthreads();
        sdata[t] += x;
        __syncthreads();
    }
    u32 run = sdata[t] - tsum;
    if (t == 255) bsum[blockIdx.x] = sdata[255];
    #pragma unroll
    for (int k = 0; k < 8; k++) {
        int i = base + k;
        if (i < M) out[i] = run;
        run += v[k];
    }
}

// fold block offsets into mscan; each block re-scans bsum (nb<=256) in LDS
__global__ void k_scanfix(u32* __restrict__ mscan,
                          const u32* __restrict__ bsum, int nb, int M) {
    __shared__ u32 sdata[256];
    __shared__ u32 sexcl[256];
    int t = threadIdx.x;
    u32 v = (t < nb) ? bsum[t] : 0u;
    sdata[t] = v;
    __syncthreads();
    for (int off = 1; off < 256; off <<= 1) {
        u32 x = (t >= off) ? sdata[t - off] : 0u;
        __syncthreads();
        sdata[t] += x;
        __syncthreads();
    }
    sexcl[t] = sdata[t] - v;
    __syncthreads();
    int i = blockIdx.x * 256 + t;
    if (i < M) mscan[i] += sexcl[i >> 11];
}

__global__ void k_place(const int* __restrict__ p, const float* __restrict__ w,
                        const u32* __restrict__ mscan,
                        u32* __restrict__ pay, unsigned char* __restrict__ loc8,
                        int E, int nblkE, int B) {
    __shared__ u32 cur[800];
    int blk = blockIdx.x;
    int t = threadIdx.x;
    for (int i = t; i < B; i += 256) cur[i] = 0;
    __syncthreads();
    int base = blk * TILE;
    #pragma unroll
    for (int k = 0; k < TILE / 256; k++) {
        int e = base + k * 256 + t;
        if (e >= 2 * E) continue;
        int src = p[e];
        int dst = (e < E) ? p[e + E] : p[e - E];
        u32 bin = (u32)dst >> 8;
        u32 w14 = (u32)(w[e] * 16384.0f + 0.5f);
        if (w14 > 16383u) w14 = 16383u;
        u32 rank = atomicAdd(&cur[bin], 1u);
        u32 slot = mscan[(size_t)bin * nblkE + blk] + rank;
        pay[slot]  = ((u32)src << 14) | w14;
        loc8[slot] = (unsigned char)((u32)dst & (BKT - 1));
    }
}

__global__ void k_bucket(const u32* __restrict__ pay,
                         const unsigned char* __restrict__ loc8,
                         const u32* __restrict__ mscan,
                         u32* __restrict__ row_ptr,
                         u32* __restrict__ colw,
                         int N, int E, int B, int nblkE) {
    __shared__ u32 hist[BKT];
    __shared__ u32 excl[BKT];
    __shared__ u32 sdata[256];
    int b = blockIdx.x;
    int t = threadIdx.x;
    int node0 = b * BKT;
    int nnodes = N - node0; if (nnodes > BKT) nnodes = BKT;
    size_t flat0 = (size_t)b * nblkE;
    u32 seg_s = mscan[flat0];
    u32 seg_e = (b + 1 < B) ? mscan[flat0 + nblkE] : (u32)(2 * E);
    hist[t] = 0;
    __syncthreads();
    for (u32 j = seg_s + t; j < seg_e; j += 256)
        atomicAdd(&hist[loc8[j]], 1u);
    __syncthreads();
    u32 tsum = hist[t];
    sdata[t] = tsum;
    __syncthreads();
    for (int off = 1; off < 256; off <<= 1) {
        u32 x = (t >= off) ? sdata[t - off] : 0u;
        __syncthreads();
        sdata[t] += x;
        __syncthreads();
    }
    u32 texcl = sdata[t] - tsum;
    excl[t] = texcl;
    if (t < nnodes) row_ptr[node0 + t] = seg_s + texcl;
    if (b == 0 && t == 0) row_ptr[N] = (u32)(2 * E);
    __syncthreads();
    for (u32 j = seg_s + t; j < seg_e; j += 256) {
        u32 loc = loc8[j];
        u32 pos = atomicAdd(&excl[loc], 1u);
        colw[seg_s + pos] = pay[j];
    }
}

// --- conv: 8 rows/wave, 8 lanes/row, lane covers dims [sub*8, sub*8+8) ----

__device__ __forceinline__ void gather8(const __half* __restrict__ x,
                                        const u32* __restrict__ colw,
                                        u32 s, u32 e, int g, int sub,
                                        float acc[8]) {
    for (u32 base = s; base < e; base += 8) {
        int m = (int)(e - base); if (m > 8) m = 8;   // valid edges this chunk
        u32 u = 0;
        if (sub < m) u = colw[base + sub];
        int   cx = (int)(u >> 14);
        float cy = (float)(u & 16383u) * (1.0f / 16384.0f);
        for (int j = 0; j < m; j++) {               // m uniform per 8-lane group
            int   sj = __shfl(cx, (g << 3) | j, 64);
            float wj = __shfl(cy, (g << 3) | j, 64);
            uint4 q = *(const uint4*)(x + (size_t)sj * DIM + sub * 8);
            const __half2* hp = (const __half2*)&q;
            #pragma unroll
            for (int k = 0; k < 4; k++) {
                float2 f = __half22float2(hp[k]);
                acc[2 * k]     += f.x * wj;
                acc[2 * k + 1] += f.y * wj;
            }
        }
    }
}

__global__ void k_conv1(const __half* __restrict__ x0h,
                        const u32* __restrict__ row_ptr,
                        const u32* __restrict__ colw,
                        __half* __restrict__ x1h, int N) {
    int wave = (blockIdx.x * 256 + threadIdx.x) >> 6;
    int g    = (threadIdx.x >> 3) & 7;
    int sub  = threadIdx.x & 7;
    int row  = wave * 8 + g;
    if (row >= N) return;
    u32 s = row_ptr[row], e = row_ptr[row + 1];
    float acc[8] = {0, 0, 0, 0, 0, 0, 0, 0};
    gather8(x0h, colw, s, e, g, sub, acc);
    float rdeno = 1.0f / fmaxf((float)(e - s), 1.0f);
    __half2 hv[4];
    #pragma unroll
    for (int k = 0; k < 4; k++) {
        float v0 = acc[2 * k] * rdeno;
        float v1 = acc[2 * k + 1] * rdeno;
        v0 = (v0 >= 0.0f) ? v0 : NEG_SLOPE * v0;
        v1 = (v1 >= 0.0f) ? v1 : NEG_SLOPE * v1;
        hv[k] = __floats2half2_rn(v0, v1);
    }
    *(uint4*)(x1h + (size_t)row * DIM + sub * 8) = *(const uint4*)hv;
}

__global__ void k_conv2(const __half* __restrict__ x0h,
                        const __half* __restrict__ x1h,
                        const u32* __restrict__ row_ptr,
                        const u32* __restrict__ colw,
                        float* __restrict__ out, int N) {
    int wave = (blockIdx.x * 256 + threadIdx.x) >> 6;
    int g    = (threadIdx.x >> 3) & 7;
    int sub  = threadIdx.x & 7;
    int row  = wave * 8 + g;
    if (row >= N) return;
    u32 s = row_ptr[row], e = row_ptr[row + 1];
    float acc[8] = {0, 0, 0, 0, 0, 0, 0, 0};
    gather8(x1h, colw, s, e, g, sub, acc);
    float rdeno = 1.0f / fmaxf((float)(e - s), 1.0f);
    uint4 q0 = *(const uint4*)(x0h + (size_t)row * DIM + sub * 8);
    uint4 q1 = *(const uint4*)(x1h + (size_t)row * DIM + sub * 8);
    const __half2* h0 = (const __half2*)&q0;
    const __half2* h1 = (const __half2*)&q1;
    float r[8];
    #pragma unroll
    for (int k = 0; k < 4; k++) {
        float2 a = __half22float2(h0[k]);
        float2 b = __half22float2(h1[k]);
        float x2a = acc[2 * k] * rdeno;
        float x2b = acc[2 * k + 1] * rdeno;
        x2a = (x2a >= 0.0f) ? x2a : NEG_SLOPE * x2a;
        x2b = (x2b >= 0.0f) ? x2b : NEG_SLOPE * x2b;
        r[2 * k]     = a.x + b.x + x2a;
        r[2 * k + 1] = a.y + b.y + x2b;
    }
    float* op = out + (size_t)row * DIM + sub * 8;
    *(float4*)(op)     = make_float4(r[0], r[1], r[2], r[3]);
    *(float4*)(op + 4) = make_float4(r[4], r[5], r[6], r[7]);
}

static inline size_t align16(size_t x) { return (x + 15) & ~(size_t)15; }

extern "C" void kernel_launch(void* const* d_in, const int* in_sizes, int n_in,
                              void* d_out, int out_size, void* d_ws, size_t ws_size,
                              hipStream_t stream) {
    const int N = in_sizes[0] / DIM;      // 200000
    const int E = in_sizes[1] / 2;        // 600000

    const float* emb = (const float*)d_in[0];
    const int*   ei  = (const int*)d_in[1];
    const float* w   = (const float*)d_in[2];
    float*       out = (float*)d_out;

    const int B     = (N + BKT - 1) / BKT;          // 782 buckets
    const int nblkE = (2 * E + TILE - 1) / TILE;    // 586 edge tiles
    const int M     = B * nblkE;                    // 458,252
    const int nb1   = (M + TILE - 1) / TILE;        // 224 (<=256)
    const int rb    = (N + 15) / 16;                // 12500 norm blocks
    const int cvb   = (N + 31) / 32;                // conv blocks: 32 rows/block

    char* ws = (char*)d_ws;
    size_t off = 0;
    __half*        x0h    = (__half*)(ws + off);        off += align16((size_t)N * DIM * 2);
    __half*        x1h    = (__half*)(ws + off);        off += align16((size_t)N * DIM * 2);
    u32*           pay    = (u32*)(ws + off);           off += align16((size_t)2 * E * 4);
    unsigned char* loc8   = (unsigned char*)(ws + off); off += align16((size_t)2 * E);
    u32*           colw   = (u32*)(ws + off);           off += align16((size_t)2 * E * 4);
    u32*           mat    = (u32*)(ws + off);           off += align16((size_t)M * 4);
    u32*           mscan  = (u32*)(ws + off);           off += align16((size_t)M * 4);
    u32*           row_ptr= (u32*)(ws + off);           off += align16((size_t)(N + 1) * 4);
    u32*           bsum   = (u32*)(ws + off);           off += align16(256 * 4);

    k_norm_hist<<<rb + nblkE, 256, 0, stream>>>(emb, x0h, ei, mat, N, E, rb, B, nblkE);
    k_scan1  <<<nb1, 256, 0, stream>>>(mat, mscan, bsum, M);
    k_scanfix<<<(M + 255) / 256, 256, 0, stream>>>(mscan, bsum, nb1, M);
    k_place  <<<nblkE, 256, 0, stream>>>(ei, w, mscan, pay, loc8, E, nblkE, B);
    k_bucket <<<B, 256, 0, stream>>>(pay, loc8, mscan, row_ptr, colw, N, E, B, nblkE);

    k_conv1<<<cvb, 256, 0, stream>>>(x0h, row_ptr, colw, x1h, N);
    k_conv2<<<cvb, 256, 0, stream>>>(x0h, x1h, row_ptr, colw, out, N);
}

// Round 3
// 244.232 us; speedup vs baseline: 1.2004x; 1.0247x over previous
//
#include <hip/hip_runtime.h>
#include <hip/hip_fp16.h>

#define DIM 64
#define NEG_SLOPE 0.01f
#define BKT 256          // nodes per bucket (LDS hist granularity in k_bucket)
#define TILEP 4096       // symmetric PAIRS per hist/place tile (= 8192 records)
#define STILE 2048       // scan1 tile: 256 thr x 8

typedef unsigned u32;
typedef unsigned long long u64;

// ---------------------------------------------------------------------------
// Round 11: k_place was 54us with 76MB WRITE_SIZE (13x amp): per-(bin,tile)
// runs were TILE/B = 2048/782 = 2.6 edges = 10B -> every run dirties a
// near-empty 64B sector. Fix: tile = 8192 records (4096 symmetric pairs ->
// p read once), runs now ~10.5 edges (42B pay + 10B loc8) -> amp ~3-4x.
// k_place uses 512-thread blocks (147 blocks, 8 indep iters/thread) to keep
// MLP at low block count. Scan shrinks 4x (M=115K). k_bucket + convs
// unchanged from R10.
// ---------------------------------------------------------------------------

__global__ void k_norm_hist(const float* __restrict__ emb,
                            __half* __restrict__ x0h,
                            const int* __restrict__ p,
                            u32* __restrict__ mat,
                            int N, int E, int rb, int B, int nblkE) {
    int t = threadIdx.x;
    if ((int)blockIdx.x < rb) {
        // L2-normalize: 16 lanes/row, 4 rows/wave, 8 waves -> 32 rows/block
        int lane = t & 63;
        int row  = blockIdx.x * 32 + (t >> 6) * 4 + (lane >> 4);
        int l16  = lane & 15;
        if (row >= N) return;
        float4 v = *(const float4*)(emb + (size_t)row * DIM + l16 * 4);
        float s = v.x * v.x + v.y * v.y + v.z * v.z + v.w * v.w;
        #pragma unroll
        for (int m = 1; m < 16; m <<= 1) s += __shfl_xor(s, m, 64);
        float inv = 1.0f / fmaxf(sqrtf(s), 1e-12f);
        union { uint2 u; __half2 h[2]; } pk;
        pk.h[0] = __floats2half2_rn(v.x * inv, v.y * inv);
        pk.h[1] = __floats2half2_rn(v.z * inv, v.w * inv);
        *(uint2*)(x0h + (size_t)row * DIM + l16 * 4) = pk.u;
    } else {
        __shared__ u32 hist[800];           // B = 782 bins
        int blk = blockIdx.x - rb;
        for (int i = t; i < B; i += 512) hist[i] = 0;
        __syncthreads();
        int base = blk * TILEP;
        #pragma unroll
        for (int k = 0; k < TILEP / 512; k++) {
            int pe = base + k * 512 + t;
            if (pe < E) {
                int a = p[pe];          // bwd record dst
                int b = p[pe + E];      // fwd record dst
                atomicAdd(&hist[(u32)b >> 8], 1u);
                atomicAdd(&hist[(u32)a >> 8], 1u);
            }
        }
        __syncthreads();
        for (int i = t; i < B; i += 512) mat[(size_t)i * nblkE + blk] = hist[i];
    }
}

__global__ void k_scan1(const u32* __restrict__ in, u32* __restrict__ out,
                        u32* __restrict__ bsum, int M) {
    __shared__ u32 sdata[256];
    int t = threadIdx.x;
    int base = blockIdx.x * STILE + t * 8;
    u32 v[8]; u32 tsum = 0;
    #pragma unroll
    for (int k = 0; k < 8; k++) {
        int i = base + k;
        v[k] = (i < M) ? in[i] : 0u;
        tsum += v[k];
    }
    sdata[t] = tsum;
    __syncthreads();
    for (int off = 1; off < 256; off <<= 1) {
        u32 x = (t >= off) ? sdata[t - off] : 0u;
        __syncthreads();
        sdata[t] += x;
        __syncthreads();
    }
    u32 run = sdata[t] - tsum;
    if (t == 255) bsum[blockIdx.x] = sdata[255];
    #pragma unroll
    for (int k = 0; k < 8; k++) {
        int i = base + k;
        if (i < M) out[i] = run;
        run += v[k];
    }
}

// fold block offsets into mscan; each block re-scans bsum (nb<=256) in LDS
__global__ void k_scanfix(u32* __restrict__ mscan,
                          const u32* __restrict__ bsum, int nb, int M) {
    __shared__ u32 sdata[256];
    __shared__ u32 sexcl[256];
    int t = threadIdx.x;
    u32 v = (t < nb) ? bsum[t] : 0u;
    sdata[t] = v;
    __syncthreads();
    for (int off = 1; off < 256; off <<= 1) {
        u32 x = (t >= off) ? sdata[t - off] : 0u;
        __syncthreads();
        sdata[t] += x;
        __syncthreads();
    }
    sexcl[t] = sdata[t] - v;
    __syncthreads();
    int i = blockIdx.x * 256 + t;
    if (i < M) mscan[i] += sexcl[i >> 11];
}

__global__ void k_place(const int* __restrict__ p, const float* __restrict__ w,
                        const u32* __restrict__ mscan,
                        u32* __restrict__ pay, unsigned char* __restrict__ loc8,
                        int E, int nblkE, int B) {
    __shared__ u32 cur[800];
    int blk = blockIdx.x;
    int t = threadIdx.x;
    for (int i = t; i < B; i += 512) cur[i] = 0;
    __syncthreads();
    int base = blk * TILEP;
    #pragma unroll
    for (int k = 0; k < TILEP / 512; k++) {
        int pe = base + k * 512 + t;
        if (pe >= E) continue;
        int a = p[pe];              // fwd: a -> b with w[pe]
        int b = p[pe + E];          // bwd: b -> a with w[pe+E]
        float wf = w[pe];
        float wb = w[pe + E];
        u32 wf14 = (u32)(wf * 16384.0f + 0.5f); if (wf14 > 16383u) wf14 = 16383u;
        u32 wb14 = (u32)(wb * 16384.0f + 0.5f); if (wb14 > 16383u) wb14 = 16383u;
        // fwd record lands in dst=b's bin
        u32 bin = (u32)b >> 8;
        u32 rank = atomicAdd(&cur[bin], 1u);
        u32 slot = mscan[(size_t)bin * nblkE + blk] + rank;
        pay[slot]  = ((u32)a << 14) | wf14;
        loc8[slot] = (unsigned char)((u32)b & (BKT - 1));
        // bwd record lands in dst=a's bin
        u32 bin2 = (u32)a >> 8;
        u32 rank2 = atomicAdd(&cur[bin2], 1u);
        u32 slot2 = mscan[(size_t)bin2 * nblkE + blk] + rank2;
        pay[slot2]  = ((u32)b << 14) | wb14;
        loc8[slot2] = (unsigned char)((u32)a & (BKT - 1));
    }
}

__global__ void k_bucket(const u32* __restrict__ pay,
                         const unsigned char* __restrict__ loc8,
                         const u32* __restrict__ mscan,
                         u32* __restrict__ row_ptr,
                         u32* __restrict__ colw,
                         int N, int E, int B, int nblkE) {
    __shared__ u32 hist[BKT];
    __shared__ u32 excl[BKT];
    __shared__ u32 sdata[256];
    int b = blockIdx.x;
    int t = threadIdx.x;
    int node0 = b * BKT;
    int nnodes = N - node0; if (nnodes > BKT) nnodes = BKT;
    size_t flat0 = (size_t)b * nblkE;
    u32 seg_s = mscan[flat0];
    u32 seg_e = (b + 1 < B) ? mscan[flat0 + nblkE] : (u32)(2 * E);
    hist[t] = 0;
    __syncthreads();
    for (u32 j = seg_s + t; j < seg_e; j += 256)
        atomicAdd(&hist[loc8[j]], 1u);
    __syncthreads();
    u32 tsum = hist[t];
    sdata[t] = tsum;
    __syncthreads();
    for (int off = 1; off < 256; off <<= 1) {
        u32 x = (t >= off) ? sdata[t - off] : 0u;
        __syncthreads();
        sdata[t] += x;
        __syncthreads();
    }
    u32 texcl = sdata[t] - tsum;
    excl[t] = texcl;
    if (t < nnodes) row_ptr[node0 + t] = seg_s + texcl;
    if (b == 0 && t == 0) row_ptr[N] = (u32)(2 * E);
    __syncthreads();
    for (u32 j = seg_s + t; j < seg_e; j += 256) {
        u32 loc = loc8[j];
        u32 pos = atomicAdd(&excl[loc], 1u);
        colw[seg_s + pos] = pay[j];
    }
}

// --- conv: 8 rows/wave, 8 lanes/row, lane covers dims [sub*8, sub*8+8) ----

__device__ __forceinline__ void gather8(const __half* __restrict__ x,
                                        const u32* __restrict__ colw,
                                        u32 s, u32 e, int g, int sub,
                                        float acc[8]) {
    for (u32 base = s; base < e; base += 8) {
        int m = (int)(e - base); if (m > 8) m = 8;   // valid edges this chunk
        u32 u = 0;
        if (sub < m) u = colw[base + sub];
        int   cx = (int)(u >> 14);
        float cy = (float)(u & 16383u) * (1.0f / 16384.0f);
        for (int j = 0; j < m; j++) {               // m uniform per 8-lane group
            int   sj = __shfl(cx, (g << 3) | j, 64);
            float wj = __shfl(cy, (g << 3) | j, 64);
            uint4 q = *(const uint4*)(x + (size_t)sj * DIM + sub * 8);
            const __half2* hp = (const __half2*)&q;
            #pragma unroll
            for (int k = 0; k < 4; k++) {
                float2 f = __half22float2(hp[k]);
                acc[2 * k]     += f.x * wj;
                acc[2 * k + 1] += f.y * wj;
            }
        }
    }
}

__global__ void k_conv1(const __half* __restrict__ x0h,
                        const u32* __restrict__ row_ptr,
                        const u32* __restrict__ colw,
                        __half* __restrict__ x1h, int N) {
    int wave = (blockIdx.x * 256 + threadIdx.x) >> 6;
    int g    = (threadIdx.x >> 3) & 7;
    int sub  = threadIdx.x & 7;
    int row  = wave * 8 + g;
    if (row >= N) return;
    u32 s = row_ptr[row], e = row_ptr[row + 1];
    float acc[8] = {0, 0, 0, 0, 0, 0, 0, 0};
    gather8(x0h, colw, s, e, g, sub, acc);
    float rdeno = 1.0f / fmaxf((float)(e - s), 1.0f);
    __half2 hv[4];
    #pragma unroll
    for (int k = 0; k < 4; k++) {
        float v0 = acc[2 * k] * rdeno;
        float v1 = acc[2 * k + 1] * rdeno;
        v0 = (v0 >= 0.0f) ? v0 : NEG_SLOPE * v0;
        v1 = (v1 >= 0.0f) ? v1 : NEG_SLOPE * v1;
        hv[k] = __floats2half2_rn(v0, v1);
    }
    *(uint4*)(x1h + (size_t)row * DIM + sub * 8) = *(const uint4*)hv;
}

__global__ void k_conv2(const __half* __restrict__ x0h,
                        const __half* __restrict__ x1h,
                        const u32* __restrict__ row_ptr,
                        const u32* __restrict__ colw,
                        float* __restrict__ out, int N) {
    int wave = (blockIdx.x * 256 + threadIdx.x) >> 6;
    int g    = (threadIdx.x >> 3) & 7;
    int sub  = threadIdx.x & 7;
    int row  = wave * 8 + g;
    if (row >= N) return;
    u32 s = row_ptr[row], e = row_ptr[row + 1];
    float acc[8] = {0, 0, 0, 0, 0, 0, 0, 0};
    gather8(x1h, colw, s, e, g, sub, acc);
    float rdeno = 1.0f / fmaxf((float)(e - s), 1.0f);
    uint4 q0 = *(const uint4*)(x0h + (size_t)row * DIM + sub * 8);
    uint4 q1 = *(const uint4*)(x1h + (size_t)row * DIM + sub * 8);
    const __half2* h0 = (const __half2*)&q0;
    const __half2* h1 = (const __half2*)&q1;
    float r[8];
    #pragma unroll
    for (int k = 0; k < 4; k++) {
        float2 a = __half22float2(h0[k]);
        float2 b = __half22float2(h1[k]);
        float x2a = acc[2 * k] * rdeno;
        float x2b = acc[2 * k + 1] * rdeno;
        x2a = (x2a >= 0.0f) ? x2a : NEG_SLOPE * x2a;
        x2b = (x2b >= 0.0f) ? x2b : NEG_SLOPE * x2b;
        r[2 * k]     = a.x + b.x + x2a;
        r[2 * k + 1] = a.y + b.y + x2b;
    }
    float* op = out + (size_t)row * DIM + sub * 8;
    *(float4*)(op)     = make_float4(r[0], r[1], r[2], r[3]);
    *(float4*)(op + 4) = make_float4(r[4], r[5], r[6], r[7]);
}

static inline size_t align16(size_t x) { return (x + 15) & ~(size_t)15; }

extern "C" void kernel_launch(void* const* d_in, const int* in_sizes, int n_in,
                              void* d_out, int out_size, void* d_ws, size_t ws_size,
                              hipStream_t stream) {
    const int N = in_sizes[0] / DIM;      // 200000
    const int E = in_sizes[1] / 2;        // 600000

    const float* emb = (const float*)d_in[0];
    const int*   ei  = (const int*)d_in[1];
    const float* w   = (const float*)d_in[2];
    float*       out = (float*)d_out;

    const int B     = (N + BKT - 1) / BKT;          // 782 buckets
    const int nblkE = (E + TILEP - 1) / TILEP;      // 147 pair tiles
    const int M     = B * nblkE;                    // 114,954
    const int nb1   = (M + STILE - 1) / STILE;      // 57 (<=256)
    const int rb    = (N + 31) / 32;                // 6250 norm blocks (512 thr)
    const int cvb   = (N + 31) / 32;                // conv blocks: 32 rows/block

    char* ws = (char*)d_ws;
    size_t off = 0;
    __half*        x0h    = (__half*)(ws + off);        off += align16((size_t)N * DIM * 2);
    __half*        x1h    = (__half*)(ws + off);        off += align16((size_t)N * DIM * 2);
    u32*           pay    = (u32*)(ws + off);           off += align16((size_t)2 * E * 4);
    unsigned char* loc8   = (unsigned char*)(ws + off); off += align16((size_t)2 * E);
    u32*           colw   = (u32*)(ws + off);           off += align16((size_t)2 * E * 4);
    u32*           mat    = (u32*)(ws + off);           off += align16((size_t)M * 4);
    u32*           mscan  = (u32*)(ws + off);           off += align16((size_t)M * 4);
    u32*           row_ptr= (u32*)(ws + off);           off += align16((size_t)(N + 1) * 4);
    u32*           bsum   = (u32*)(ws + off);           off += align16(256 * 4);

    k_norm_hist<<<rb + nblkE, 512, 0, stream>>>(emb, x0h, ei, mat, N, E, rb, B, nblkE);
    k_scan1  <<<nb1, 256, 0, stream>>>(mat, mscan, bsum, M);
    k_scanfix<<<(M + 255) / 256, 256, 0, stream>>>(mscan, bsum, nb1, M);
    k_place  <<<nblkE, 512, 0, stream>>>(ei, w, mscan, pay, loc8, E, nblkE, B);
    k_bucket <<<B, 256, 0, stream>>>(pay, loc8, mscan, row_ptr, colw, N, E, B, nblkE);

    k_conv1<<<cvb, 256, 0, stream>>>(x0h, row_ptr, colw, x1h, N);
    k_conv2<<<cvb, 256, 0, stream>>>(x0h, x1h, row_ptr, colw, out, N);
}

// Round 4
// 210.680 us; speedup vs baseline: 1.3916x; 1.1593x over previous
//
#include <hip/hip_runtime.h>
#include <hip/hip_fp16.h>

#define DIM 64
#define NEG_SLOPE 0.01f
#define BKT 256          // nodes per bucket (LDS hist granularity in k_bucket)
#define TILEP 4096       // symmetric PAIRS per hist/place tile (= 8192 records)
#define RECS (TILEP * 2) // records per tile
#define STILE 2048       // scan1 tile: 256 thr x 8

typedef unsigned u32;
typedef unsigned short u16;
typedef unsigned char u8;

// ---------------------------------------------------------------------------
// Round 12: k_place was 52us at 9% occupancy, VGPR=8, 1.1TB/s: each record
// was an exposed serial chain (LDS-atomic rank -> dependent random mscan
// load -> scattered 4B store = 64 line-transactions/wave-store). Fix: sort
// the 8192-record tile IN LDS (stage -> 1024-bin scan -> perm[] ), preload
// the tile's mscan column once (782 loads), then write out in staging order:
// gslot = j + delta[bin], consecutive lanes -> consecutive slots. No
// dependent global load in the store path, runs written coalesced, lines
// assembled in L2. hist/scan/bucket/convs unchanged.
// ---------------------------------------------------------------------------

__global__ void k_norm_hist(const float* __restrict__ emb,
                            __half* __restrict__ x0h,
                            const int* __restrict__ p,
                            u32* __restrict__ mat,
                            int N, int E, int rb, int B, int nblkE) {
    int t = threadIdx.x;
    if ((int)blockIdx.x < rb) {
        // L2-normalize: 16 lanes/row, 4 rows/wave, 8 waves -> 32 rows/block
        int lane = t & 63;
        int row  = blockIdx.x * 32 + (t >> 6) * 4 + (lane >> 4);
        int l16  = lane & 15;
        if (row >= N) return;
        float4 v = *(const float4*)(emb + (size_t)row * DIM + l16 * 4);
        float s = v.x * v.x + v.y * v.y + v.z * v.z + v.w * v.w;
        #pragma unroll
        for (int m = 1; m < 16; m <<= 1) s += __shfl_xor(s, m, 64);
        float inv = 1.0f / fmaxf(sqrtf(s), 1e-12f);
        union { uint2 u; __half2 h[2]; } pk;
        pk.h[0] = __floats2half2_rn(v.x * inv, v.y * inv);
        pk.h[1] = __floats2half2_rn(v.z * inv, v.w * inv);
        *(uint2*)(x0h + (size_t)row * DIM + l16 * 4) = pk.u;
    } else {
        __shared__ u32 hist[800];           // B = 782 bins
        int blk = blockIdx.x - rb;
        for (int i = t; i < B; i += 512) hist[i] = 0;
        __syncthreads();
        int base = blk * TILEP;
        #pragma unroll
        for (int k = 0; k < TILEP / 512; k++) {
            int pe = base + k * 512 + t;
            if (pe < E) {
                int a = p[pe];
                int b = p[pe + E];
                atomicAdd(&hist[(u32)b >> 8], 1u);
                atomicAdd(&hist[(u32)a >> 8], 1u);
            }
        }
        __syncthreads();
        for (int i = t; i < B; i += 512) mat[(size_t)i * nblkE + blk] = hist[i];
    }
}

__global__ void k_scan1(const u32* __restrict__ in, u32* __restrict__ out,
                        u32* __restrict__ bsum, int M) {
    __shared__ u32 sdata[256];
    int t = threadIdx.x;
    int base = blockIdx.x * STILE + t * 8;
    u32 v[8]; u32 tsum = 0;
    #pragma unroll
    for (int k = 0; k < 8; k++) {
        int i = base + k;
        v[k] = (i < M) ? in[i] : 0u;
        tsum += v[k];
    }
    sdata[t] = tsum;
    __syncthreads();
    for (int off = 1; off < 256; off <<= 1) {
        u32 x = (t >= off) ? sdata[t - off] : 0u;
        __syncthreads();
        sdata[t] += x;
        __syncthreads();
    }
    u32 run = sdata[t] - tsum;
    if (t == 255) bsum[blockIdx.x] = sdata[255];
    #pragma unroll
    for (int k = 0; k < 8; k++) {
        int i = base + k;
        if (i < M) out[i] = run;
        run += v[k];
    }
}

// fold block offsets into mscan; each block re-scans bsum (nb<=256) in LDS
__global__ void k_scanfix(u32* __restrict__ mscan,
                          const u32* __restrict__ bsum, int nb, int M) {
    __shared__ u32 sdata[256];
    __shared__ u32 sexcl[256];
    int t = threadIdx.x;
    u32 v = (t < nb) ? bsum[t] : 0u;
    sdata[t] = v;
    __syncthreads();
    for (int off = 1; off < 256; off <<= 1) {
        u32 x = (t >= off) ? sdata[t - off] : 0u;
        __syncthreads();
        sdata[t] += x;
        __syncthreads();
    }
    sexcl[t] = sdata[t] - v;
    __syncthreads();
    int i = blockIdx.x * 256 + t;
    if (i < M) mscan[i] += sexcl[i >> 11];
}

// LDS tile sort + coalesced run write-out. ~94KB LDS, 1 block/CU.
__global__ __launch_bounds__(512, 1)
void k_place(const int* __restrict__ p, const float* __restrict__ w,
             const u32* __restrict__ mscan,
             u32* __restrict__ pay, u8* __restrict__ loc8,
             int E, int nblkE, int B) {
    __shared__ u32 sPay[RECS];    // 32KB
    __shared__ u32 sMeta[RECS];   // 32KB (= dst node id; bin=>>8, loc=&255)
    __shared__ u16 sPerm[RECS];   // 16KB
    __shared__ u32 hist[1024];    // counts -> (rezeroed) cursors
    __shared__ u32 sstart[1024];
    __shared__ u32 delta[1024];
    __shared__ u32 sdata[512];

    int blk = blockIdx.x;
    int t = threadIdx.x;
    int base = blk * TILEP;
    int rem = E - base;                       // pairs in this tile
    int vlim = rem * 2; if (vlim > RECS) vlim = RECS;

    hist[t] = 0; hist[t + 512] = 0;
    __syncthreads();

    // pass A: stage records + count bins
    #pragma unroll
    for (int k = 0; k < TILEP / 512; k++) {
        int pe = base + k * 512 + t;
        if (pe < E) {
            int a = p[pe];
            int b = p[pe + E];
            float wf = w[pe];
            float wb = w[pe + E];
            u32 wf14 = (u32)(wf * 16384.0f + 0.5f); if (wf14 > 16383u) wf14 = 16383u;
            u32 wb14 = (u32)(wb * 16384.0f + 0.5f); if (wb14 > 16383u) wb14 = 16383u;
            int li = (k * 512 + t) * 2;
            sPay[li]      = ((u32)a << 14) | wf14;   // fwd record: dst = b
            sMeta[li]     = (u32)b;
            sPay[li + 1]  = ((u32)b << 14) | wb14;   // bwd record: dst = a
            sMeta[li + 1] = (u32)a;
            atomicAdd(&hist[(u32)b >> 8], 1u);
            atomicAdd(&hist[(u32)a >> 8], 1u);
        }
    }
    __syncthreads();

    // scan 1024 bins (2 per thread) -> sstart (exclusive)
    u32 a0 = hist[2 * t], a1 = hist[2 * t + 1];
    u32 tsum = a0 + a1;
    sdata[t] = tsum;
    __syncthreads();
    for (int off = 1; off < 512; off <<= 1) {
        u32 x = (t >= off) ? sdata[t - off] : 0u;
        __syncthreads();
        sdata[t] += x;
        __syncthreads();
    }
    u32 texcl = sdata[t] - tsum;
    sstart[2 * t]     = texcl;
    sstart[2 * t + 1] = texcl + a0;
    __syncthreads();

    // rezero hist (becomes rank cursor) + load this tile's mscan column
    hist[t] = 0; hist[t + 512] = 0;
    for (int i = t; i < B; i += 512)
        delta[i] = mscan[(size_t)i * nblkE + blk] - sstart[i];
    __syncthreads();

    // pass B: build permutation (staging order sorted by bin)
    #pragma unroll
    for (int k = 0; k < RECS / 512; k++) {
        int li = k * 512 + t;
        if (li < vlim) {
            u32 bin = sMeta[li] >> 8;
            u32 r = atomicAdd(&hist[bin], 1u);
            sPerm[sstart[bin] + r] = (u16)li;
        }
    }
    __syncthreads();

    // pass C: write out in sorted order; consecutive j -> consecutive gslot
    #pragma unroll
    for (int k = 0; k < RECS / 512; k++) {
        int j = k * 512 + t;
        if (j < vlim) {
            int li = sPerm[j];
            u32 pv = sPay[li];
            u32 mt = sMeta[li];
            u32 gs = (u32)j + delta[mt >> 8];   // = mscan base + rank (u32 wrap ok)
            pay[gs]  = pv;
            loc8[gs] = (u8)(mt & 255u);
        }
    }
}

__global__ void k_bucket(const u32* __restrict__ pay,
                         const u8* __restrict__ loc8,
                         const u32* __restrict__ mscan,
                         u32* __restrict__ row_ptr,
                         u32* __restrict__ colw,
                         int N, int E, int B, int nblkE) {
    __shared__ u32 hist[BKT];
    __shared__ u32 excl[BKT];
    __shared__ u32 sdata[256];
    int b = blockIdx.x;
    int t = threadIdx.x;
    int node0 = b * BKT;
    int nnodes = N - node0; if (nnodes > BKT) nnodes = BKT;
    size_t flat0 = (size_t)b * nblkE;
    u32 seg_s = mscan[flat0];
    u32 seg_e = (b + 1 < B) ? mscan[flat0 + nblkE] : (u32)(2 * E);
    hist[t] = 0;
    __syncthreads();
    for (u32 j = seg_s + t; j < seg_e; j += 256)
        atomicAdd(&hist[loc8[j]], 1u);
    __syncthreads();
    u32 tsum = hist[t];
    sdata[t] = tsum;
    __syncthreads();
    for (int off = 1; off < 256; off <<= 1) {
        u32 x = (t >= off) ? sdata[t - off] : 0u;
        __syncthreads();
        sdata[t] += x;
        __syncthreads();
    }
    u32 texcl = sdata[t] - tsum;
    excl[t] = texcl;
    if (t < nnodes) row_ptr[node0 + t] = seg_s + texcl;
    if (b == 0 && t == 0) row_ptr[N] = (u32)(2 * E);
    __syncthreads();
    for (u32 j = seg_s + t; j < seg_e; j += 256) {
        u32 loc = loc8[j];
        u32 pos = atomicAdd(&excl[loc], 1u);
        colw[seg_s + pos] = pay[j];
    }
}

// --- conv: 8 rows/wave, 8 lanes/row, lane covers dims [sub*8, sub*8+8) ----

__device__ __forceinline__ void gather8(const __half* __restrict__ x,
                                        const u32* __restrict__ colw,
                                        u32 s, u32 e, int g, int sub,
                                        float acc[8]) {
    for (u32 base = s; base < e; base += 8) {
        int m = (int)(e - base); if (m > 8) m = 8;   // valid edges this chunk
        u32 u = 0;
        if (sub < m) u = colw[base + sub];
        int   cx = (int)(u >> 14);
        float cy = (float)(u & 16383u) * (1.0f / 16384.0f);
        for (int j = 0; j < m; j++) {               // m uniform per 8-lane group
            int   sj = __shfl(cx, (g << 3) | j, 64);
            float wj = __shfl(cy, (g << 3) | j, 64);
            uint4 q = *(const uint4*)(x + (size_t)sj * DIM + sub * 8);
            const __half2* hp = (const __half2*)&q;
            #pragma unroll
            for (int k = 0; k < 4; k++) {
                float2 f = __half22float2(hp[k]);
                acc[2 * k]     += f.x * wj;
                acc[2 * k + 1] += f.y * wj;
            }
        }
    }
}

__global__ void k_conv1(const __half* __restrict__ x0h,
                        const u32* __restrict__ row_ptr,
                        const u32* __restrict__ colw,
                        __half* __restrict__ x1h, int N) {
    int wave = (blockIdx.x * 256 + threadIdx.x) >> 6;
    int g    = (threadIdx.x >> 3) & 7;
    int sub  = threadIdx.x & 7;
    int row  = wave * 8 + g;
    if (row >= N) return;
    u32 s = row_ptr[row], e = row_ptr[row + 1];
    float acc[8] = {0, 0, 0, 0, 0, 0, 0, 0};
    gather8(x0h, colw, s, e, g, sub, acc);
    float rdeno = 1.0f / fmaxf((float)(e - s), 1.0f);
    __half2 hv[4];
    #pragma unroll
    for (int k = 0; k < 4; k++) {
        float v0 = acc[2 * k] * rdeno;
        float v1 = acc[2 * k + 1] * rdeno;
        v0 = (v0 >= 0.0f) ? v0 : NEG_SLOPE * v0;
        v1 = (v1 >= 0.0f) ? v1 : NEG_SLOPE * v1;
        hv[k] = __floats2half2_rn(v0, v1);
    }
    *(uint4*)(x1h + (size_t)row * DIM + sub * 8) = *(const uint4*)hv;
}

__global__ void k_conv2(const __half* __restrict__ x0h,
                        const __half* __restrict__ x1h,
                        const u32* __restrict__ row_ptr,
                        const u32* __restrict__ colw,
                        float* __restrict__ out, int N) {
    int wave = (blockIdx.x * 256 + threadIdx.x) >> 6;
    int g    = (threadIdx.x >> 3) & 7;
    int sub  = threadIdx.x & 7;
    int row  = wave * 8 + g;
    if (row >= N) return;
    u32 s = row_ptr[row], e = row_ptr[row + 1];
    float acc[8] = {0, 0, 0, 0, 0, 0, 0, 0};
    gather8(x1h, colw, s, e, g, sub, acc);
    float rdeno = 1.0f / fmaxf((float)(e - s), 1.0f);
    uint4 q0 = *(const uint4*)(x0h + (size_t)row * DIM + sub * 8);
    uint4 q1 = *(const uint4*)(x1h + (size_t)row * DIM + sub * 8);
    const __half2* h0 = (const __half2*)&q0;
    const __half2* h1 = (const __half2*)&q1;
    float r[8];
    #pragma unroll
    for (int k = 0; k < 4; k++) {
        float2 a = __half22float2(h0[k]);
        float2 b = __half22float2(h1[k]);
        float x2a = acc[2 * k] * rdeno;
        float x2b = acc[2 * k + 1] * rdeno;
        x2a = (x2a >= 0.0f) ? x2a : NEG_SLOPE * x2a;
        x2b = (x2b >= 0.0f) ? x2b : NEG_SLOPE * x2b;
        r[2 * k]     = a.x + b.x + x2a;
        r[2 * k + 1] = a.y + b.y + x2b;
    }
    float* op = out + (size_t)row * DIM + sub * 8;
    *(float4*)(op)     = make_float4(r[0], r[1], r[2], r[3]);
    *(float4*)(op + 4) = make_float4(r[4], r[5], r[6], r[7]);
}

static inline size_t align16(size_t x) { return (x + 15) & ~(size_t)15; }

extern "C" void kernel_launch(void* const* d_in, const int* in_sizes, int n_in,
                              void* d_out, int out_size, void* d_ws, size_t ws_size,
                              hipStream_t stream) {
    const int N = in_sizes[0] / DIM;      // 200000
    const int E = in_sizes[1] / 2;        // 600000

    const float* emb = (const float*)d_in[0];
    const int*   ei  = (const int*)d_in[1];
    const float* w   = (const float*)d_in[2];
    float*       out = (float*)d_out;

    const int B     = (N + BKT - 1) / BKT;          // 782 buckets
    const int nblkE = (E + TILEP - 1) / TILEP;      // 147 pair tiles
    const int M     = B * nblkE;                    // 114,954
    const int nb1   = (M + STILE - 1) / STILE;      // 57 (<=256)
    const int rb    = (N + 31) / 32;                // 6250 norm blocks (512 thr)
    const int cvb   = (N + 31) / 32;                // conv blocks: 32 rows/block

    char* ws = (char*)d_ws;
    size_t off = 0;
    __half* x0h    = (__half*)(ws + off); off += align16((size_t)N * DIM * 2);
    __half* x1h    = (__half*)(ws + off); off += align16((size_t)N * DIM * 2);
    u32*    pay    = (u32*)(ws + off);    off += align16((size_t)2 * E * 4);
    u8*     loc8   = (u8*)(ws + off);     off += align16((size_t)2 * E);
    u32*    colw   = (u32*)(ws + off);    off += align16((size_t)2 * E * 4);
    u32*    mat    = (u32*)(ws + off);    off += align16((size_t)M * 4);
    u32*    mscan  = (u32*)(ws + off);    off += align16((size_t)M * 4);
    u32*    row_ptr= (u32*)(ws + off);    off += align16((size_t)(N + 1) * 4);
    u32*    bsum   = (u32*)(ws + off);    off += align16(256 * 4);

    k_norm_hist<<<rb + nblkE, 512, 0, stream>>>(emb, x0h, ei, mat, N, E, rb, B, nblkE);
    k_scan1  <<<nb1, 256, 0, stream>>>(mat, mscan, bsum, M);
    k_scanfix<<<(M + 255) / 256, 256, 0, stream>>>(mscan, bsum, nb1, M);
    k_place  <<<nblkE, 512, 0, stream>>>(ei, w, mscan, pay, loc8, E, nblkE, B);
    k_bucket <<<B, 256, 0, stream>>>(pay, loc8, mscan, row_ptr, colw, N, E, B, nblkE);

    k_conv1<<<cvb, 256, 0, stream>>>(x0h, row_ptr, colw, x1h, N);
    k_conv2<<<cvb, 256, 0, stream>>>(x0h, x1h, row_ptr, colw, out, N);
}

// Round 5
// 204.081 us; speedup vs baseline: 1.4366x; 1.0323x over previous
//
#include <hip/hip_runtime.h>
#include <hip/hip_fp16.h>

#define DIM 64
#define NEG_SLOPE 0.01f
#define BKT 256          // nodes per bucket (LDS hist granularity in k_bucket)
#define TILEP 4096       // symmetric PAIRS per hist/place tile (= 8192 records)
#define RECS (TILEP * 2) // records per tile
#define STILE 2048       // scan1 tile: 256 thr x 8

typedef unsigned u32;
typedef unsigned short u16;
typedef unsigned char u8;

// ---------------------------------------------------------------------------
// Round 13: conv2 was 41.5us, VGPR=20, VALUBusy 26%, 3.6TB/s: the gather
// inner loop held ~1 uint4 in flight (4 VGPRs each), so each row was ~6
// serialized L2/L3-miss latencies. Fix: batch 4 independent gather loads
// (static q0..q3, predicated — no runtime-indexed arrays) before consuming;
// hoist conv2's own-row x0h/x1h loads ahead of the gather. Same FMA order
// -> identical numerics. Build pipeline unchanged from R12.
// ---------------------------------------------------------------------------

__global__ void k_norm_hist(const float* __restrict__ emb,
                            __half* __restrict__ x0h,
                            const int* __restrict__ p,
                            u32* __restrict__ mat,
                            int N, int E, int rb, int B, int nblkE) {
    int t = threadIdx.x;
    if ((int)blockIdx.x < rb) {
        // L2-normalize: 16 lanes/row, 4 rows/wave, 8 waves -> 32 rows/block
        int lane = t & 63;
        int row  = blockIdx.x * 32 + (t >> 6) * 4 + (lane >> 4);
        int l16  = lane & 15;
        if (row >= N) return;
        float4 v = *(const float4*)(emb + (size_t)row * DIM + l16 * 4);
        float s = v.x * v.x + v.y * v.y + v.z * v.z + v.w * v.w;
        #pragma unroll
        for (int m = 1; m < 16; m <<= 1) s += __shfl_xor(s, m, 64);
        float inv = 1.0f / fmaxf(sqrtf(s), 1e-12f);
        union { uint2 u; __half2 h[2]; } pk;
        pk.h[0] = __floats2half2_rn(v.x * inv, v.y * inv);
        pk.h[1] = __floats2half2_rn(v.z * inv, v.w * inv);
        *(uint2*)(x0h + (size_t)row * DIM + l16 * 4) = pk.u;
    } else {
        __shared__ u32 hist[800];           // B = 782 bins
        int blk = blockIdx.x - rb;
        for (int i = t; i < B; i += 512) hist[i] = 0;
        __syncthreads();
        int base = blk * TILEP;
        #pragma unroll
        for (int k = 0; k < TILEP / 512; k++) {
            int pe = base + k * 512 + t;
            if (pe < E) {
                int a = p[pe];
                int b = p[pe + E];
                atomicAdd(&hist[(u32)b >> 8], 1u);
                atomicAdd(&hist[(u32)a >> 8], 1u);
            }
        }
        __syncthreads();
        for (int i = t; i < B; i += 512) mat[(size_t)i * nblkE + blk] = hist[i];
    }
}

__global__ void k_scan1(const u32* __restrict__ in, u32* __restrict__ out,
                        u32* __restrict__ bsum, int M) {
    __shared__ u32 sdata[256];
    int t = threadIdx.x;
    int base = blockIdx.x * STILE + t * 8;
    u32 v[8]; u32 tsum = 0;
    #pragma unroll
    for (int k = 0; k < 8; k++) {
        int i = base + k;
        v[k] = (i < M) ? in[i] : 0u;
        tsum += v[k];
    }
    sdata[t] = tsum;
    __syncthreads();
    for (int off = 1; off < 256; off <<= 1) {
        u32 x = (t >= off) ? sdata[t - off] : 0u;
        __syncthreads();
        sdata[t] += x;
        __syncthreads();
    }
    u32 run = sdata[t] - tsum;
    if (t == 255) bsum[blockIdx.x] = sdata[255];
    #pragma unroll
    for (int k = 0; k < 8; k++) {
        int i = base + k;
        if (i < M) out[i] = run;
        run += v[k];
    }
}

// fold block offsets into mscan; each block re-scans bsum (nb<=256) in LDS
__global__ void k_scanfix(u32* __restrict__ mscan,
                          const u32* __restrict__ bsum, int nb, int M) {
    __shared__ u32 sdata[256];
    __shared__ u32 sexcl[256];
    int t = threadIdx.x;
    u32 v = (t < nb) ? bsum[t] : 0u;
    sdata[t] = v;
    __syncthreads();
    for (int off = 1; off < 256; off <<= 1) {
        u32 x = (t >= off) ? sdata[t - off] : 0u;
        __syncthreads();
        sdata[t] += x;
        __syncthreads();
    }
    sexcl[t] = sdata[t] - v;
    __syncthreads();
    int i = blockIdx.x * 256 + t;
    if (i < M) mscan[i] += sexcl[i >> 11];
}

// LDS tile sort + coalesced run write-out. ~94KB LDS, 1 block/CU.
__global__ __launch_bounds__(512, 1)
void k_place(const int* __restrict__ p, const float* __restrict__ w,
             const u32* __restrict__ mscan,
             u32* __restrict__ pay, u8* __restrict__ loc8,
             int E, int nblkE, int B) {
    __shared__ u32 sPay[RECS];    // 32KB
    __shared__ u32 sMeta[RECS];   // 32KB (= dst node id; bin=>>8, loc=&255)
    __shared__ u16 sPerm[RECS];   // 16KB
    __shared__ u32 hist[1024];    // counts -> (rezeroed) cursors
    __shared__ u32 sstart[1024];
    __shared__ u32 delta[1024];
    __shared__ u32 sdata[512];

    int blk = blockIdx.x;
    int t = threadIdx.x;
    int base = blk * TILEP;
    int rem = E - base;                       // pairs in this tile
    int vlim = rem * 2; if (vlim > RECS) vlim = RECS;

    hist[t] = 0; hist[t + 512] = 0;
    __syncthreads();

    // pass A: stage records + count bins
    #pragma unroll
    for (int k = 0; k < TILEP / 512; k++) {
        int pe = base + k * 512 + t;
        if (pe < E) {
            int a = p[pe];
            int b = p[pe + E];
            float wf = w[pe];
            float wb = w[pe + E];
            u32 wf14 = (u32)(wf * 16384.0f + 0.5f); if (wf14 > 16383u) wf14 = 16383u;
            u32 wb14 = (u32)(wb * 16384.0f + 0.5f); if (wb14 > 16383u) wb14 = 16383u;
            int li = (k * 512 + t) * 2;
            sPay[li]      = ((u32)a << 14) | wf14;   // fwd record: dst = b
            sMeta[li]     = (u32)b;
            sPay[li + 1]  = ((u32)b << 14) | wb14;   // bwd record: dst = a
            sMeta[li + 1] = (u32)a;
            atomicAdd(&hist[(u32)b >> 8], 1u);
            atomicAdd(&hist[(u32)a >> 8], 1u);
        }
    }
    __syncthreads();

    // scan 1024 bins (2 per thread) -> sstart (exclusive)
    u32 a0 = hist[2 * t], a1 = hist[2 * t + 1];
    u32 tsum = a0 + a1;
    sdata[t] = tsum;
    __syncthreads();
    for (int off = 1; off < 512; off <<= 1) {
        u32 x = (t >= off) ? sdata[t - off] : 0u;
        __syncthreads();
        sdata[t] += x;
        __syncthreads();
    }
    u32 texcl = sdata[t] - tsum;
    sstart[2 * t]     = texcl;
    sstart[2 * t + 1] = texcl + a0;
    __syncthreads();

    // rezero hist (becomes rank cursor) + load this tile's mscan column
    hist[t] = 0; hist[t + 512] = 0;
    for (int i = t; i < B; i += 512)
        delta[i] = mscan[(size_t)i * nblkE + blk] - sstart[i];
    __syncthreads();

    // pass B: build permutation (staging order sorted by bin)
    #pragma unroll
    for (int k = 0; k < RECS / 512; k++) {
        int li = k * 512 + t;
        if (li < vlim) {
            u32 bin = sMeta[li] >> 8;
            u32 r = atomicAdd(&hist[bin], 1u);
            sPerm[sstart[bin] + r] = (u16)li;
        }
    }
    __syncthreads();

    // pass C: write out in sorted order; consecutive j -> consecutive gslot
    #pragma unroll
    for (int k = 0; k < RECS / 512; k++) {
        int j = k * 512 + t;
        if (j < vlim) {
            int li = sPerm[j];
            u32 pv = sPay[li];
            u32 mt = sMeta[li];
            u32 gs = (u32)j + delta[mt >> 8];   // = mscan base + rank (u32 wrap ok)
            pay[gs]  = pv;
            loc8[gs] = (u8)(mt & 255u);
        }
    }
}

__global__ void k_bucket(const u32* __restrict__ pay,
                         const u8* __restrict__ loc8,
                         const u32* __restrict__ mscan,
                         u32* __restrict__ row_ptr,
                         u32* __restrict__ colw,
                         int N, int E, int B, int nblkE) {
    __shared__ u32 hist[BKT];
    __shared__ u32 excl[BKT];
    __shared__ u32 sdata[256];
    int b = blockIdx.x;
    int t = threadIdx.x;
    int node0 = b * BKT;
    int nnodes = N - node0; if (nnodes > BKT) nnodes = BKT;
    size_t flat0 = (size_t)b * nblkE;
    u32 seg_s = mscan[flat0];
    u32 seg_e = (b + 1 < B) ? mscan[flat0 + nblkE] : (u32)(2 * E);
    hist[t] = 0;
    __syncthreads();
    for (u32 j = seg_s + t; j < seg_e; j += 256)
        atomicAdd(&hist[loc8[j]], 1u);
    __syncthreads();
    u32 tsum = hist[t];
    sdata[t] = tsum;
    __syncthreads();
    for (int off = 1; off < 256; off <<= 1) {
        u32 x = (t >= off) ? sdata[t - off] : 0u;
        __syncthreads();
        sdata[t] += x;
        __syncthreads();
    }
    u32 texcl = sdata[t] - tsum;
    excl[t] = texcl;
    if (t < nnodes) row_ptr[node0 + t] = seg_s + texcl;
    if (b == 0 && t == 0) row_ptr[N] = (u32)(2 * E);
    __syncthreads();
    for (u32 j = seg_s + t; j < seg_e; j += 256) {
        u32 loc = loc8[j];
        u32 pos = atomicAdd(&excl[loc], 1u);
        colw[seg_s + pos] = pay[j];
    }
}

// --- conv: 8 rows/wave, 8 lanes/row, lane covers dims [sub*8, sub*8+8) ----

__device__ __forceinline__ void fma8(const uint4& q, float wj, float acc[8]) {
    const __half2* hp = (const __half2*)&q;
    #pragma unroll
    for (int k = 0; k < 4; k++) {
        float2 f = __half22float2(hp[k]);
        acc[2 * k]     += f.x * wj;
        acc[2 * k + 1] += f.y * wj;
    }
}

__device__ __forceinline__ void gather8(const __half* __restrict__ x,
                                        const u32* __restrict__ colw,
                                        u32 s, u32 e, int g, int sub,
                                        float acc[8]) {
    for (u32 base = s; base < e; base += 8) {
        int m = (int)(e - base); if (m > 8) m = 8;   // valid edges this chunk
        u32 u = 0;
        if (sub < m) u = colw[base + sub];
        int   cx = (int)(u >> 14);
        float cy = (float)(u & 16383u) * (1.0f / 16384.0f);
        int lb = (g << 3);
        for (int j0 = 0; j0 < m; j0 += 4) {
            // batch-issue up to 4 independent 16B loads, THEN consume.
            // static names + predication: no runtime-indexed array -> no scratch.
            uint4 q0, q1, q2, q3;
            if (j0 + 0 < m) { int sj = __shfl(cx, lb + j0 + 0, 64);
                              q0 = *(const uint4*)(x + (size_t)sj * DIM + sub * 8); }
            if (j0 + 1 < m) { int sj = __shfl(cx, lb + j0 + 1, 64);
                              q1 = *(const uint4*)(x + (size_t)sj * DIM + sub * 8); }
            if (j0 + 2 < m) { int sj = __shfl(cx, lb + j0 + 2, 64);
                              q2 = *(const uint4*)(x + (size_t)sj * DIM + sub * 8); }
            if (j0 + 3 < m) { int sj = __shfl(cx, lb + j0 + 3, 64);
                              q3 = *(const uint4*)(x + (size_t)sj * DIM + sub * 8); }
            if (j0 + 0 < m) { float wj = __shfl(cy, lb + j0 + 0, 64); fma8(q0, wj, acc); }
            if (j0 + 1 < m) { float wj = __shfl(cy, lb + j0 + 1, 64); fma8(q1, wj, acc); }
            if (j0 + 2 < m) { float wj = __shfl(cy, lb + j0 + 2, 64); fma8(q2, wj, acc); }
            if (j0 + 3 < m) { float wj = __shfl(cy, lb + j0 + 3, 64); fma8(q3, wj, acc); }
        }
    }
}

__global__ void k_conv1(const __half* __restrict__ x0h,
                        const u32* __restrict__ row_ptr,
                        const u32* __restrict__ colw,
                        __half* __restrict__ x1h, int N) {
    int wave = (blockIdx.x * 256 + threadIdx.x) >> 6;
    int g    = (threadIdx.x >> 3) & 7;
    int sub  = threadIdx.x & 7;
    int row  = wave * 8 + g;
    if (row >= N) return;
    u32 s = row_ptr[row], e = row_ptr[row + 1];
    float acc[8] = {0, 0, 0, 0, 0, 0, 0, 0};
    gather8(x0h, colw, s, e, g, sub, acc);
    float rdeno = 1.0f / fmaxf((float)(e - s), 1.0f);
    __half2 hv[4];
    #pragma unroll
    for (int k = 0; k < 4; k++) {
        float v0 = acc[2 * k] * rdeno;
        float v1 = acc[2 * k + 1] * rdeno;
        v0 = (v0 >= 0.0f) ? v0 : NEG_SLOPE * v0;
        v1 = (v1 >= 0.0f) ? v1 : NEG_SLOPE * v1;
        hv[k] = __floats2half2_rn(v0, v1);
    }
    *(uint4*)(x1h + (size_t)row * DIM + sub * 8) = *(const uint4*)hv;
}

__global__ void k_conv2(const __half* __restrict__ x0h,
                        const __half* __restrict__ x1h,
                        const u32* __restrict__ row_ptr,
                        const u32* __restrict__ colw,
                        float* __restrict__ out, int N) {
    int wave = (blockIdx.x * 256 + threadIdx.x) >> 6;
    int g    = (threadIdx.x >> 3) & 7;
    int sub  = threadIdx.x & 7;
    int row  = wave * 8 + g;
    if (row >= N) return;
    u32 s = row_ptr[row], e = row_ptr[row + 1];
    // hoist own-row loads so they overlap the gather latency
    uint4 q0 = *(const uint4*)(x0h + (size_t)row * DIM + sub * 8);
    uint4 q1 = *(const uint4*)(x1h + (size_t)row * DIM + sub * 8);
    float acc[8] = {0, 0, 0, 0, 0, 0, 0, 0};
    gather8(x1h, colw, s, e, g, sub, acc);
    float rdeno = 1.0f / fmaxf((float)(e - s), 1.0f);
    const __half2* h0 = (const __half2*)&q0;
    const __half2* h1 = (const __half2*)&q1;
    float r[8];
    #pragma unroll
    for (int k = 0; k < 4; k++) {
        float2 a = __half22float2(h0[k]);
        float2 b = __half22float2(h1[k]);
        float x2a = acc[2 * k] * rdeno;
        float x2b = acc[2 * k + 1] * rdeno;
        x2a = (x2a >= 0.0f) ? x2a : NEG_SLOPE * x2a;
        x2b = (x2b >= 0.0f) ? x2b : NEG_SLOPE * x2b;
        r[2 * k]     = a.x + b.x + x2a;
        r[2 * k + 1] = a.y + b.y + x2b;
    }
    float* op = out + (size_t)row * DIM + sub * 8;
    *(float4*)(op)     = make_float4(r[0], r[1], r[2], r[3]);
    *(float4*)(op + 4) = make_float4(r[4], r[5], r[6], r[7]);
}

static inline size_t align16(size_t x) { return (x + 15) & ~(size_t)15; }

extern "C" void kernel_launch(void* const* d_in, const int* in_sizes, int n_in,
                              void* d_out, int out_size, void* d_ws, size_t ws_size,
                              hipStream_t stream) {
    const int N = in_sizes[0] / DIM;      // 200000
    const int E = in_sizes[1] / 2;        // 600000

    const float* emb = (const float*)d_in[0];
    const int*   ei  = (const int*)d_in[1];
    const float* w   = (const float*)d_in[2];
    float*       out = (float*)d_out;

    const int B     = (N + BKT - 1) / BKT;          // 782 buckets
    const int nblkE = (E + TILEP - 1) / TILEP;      // 147 pair tiles
    const int M     = B * nblkE;                    // 114,954
    const int nb1   = (M + STILE - 1) / STILE;      // 57 (<=256)
    const int rb    = (N + 31) / 32;                // 6250 norm blocks (512 thr)
    const int cvb   = (N + 31) / 32;                // conv blocks: 32 rows/block

    char* ws = (char*)d_ws;
    size_t off = 0;
    __half* x0h    = (__half*)(ws + off); off += align16((size_t)N * DIM * 2);
    __half* x1h    = (__half*)(ws + off); off += align16((size_t)N * DIM * 2);
    u32*    pay    = (u32*)(ws + off);    off += align16((size_t)2 * E * 4);
    u8*     loc8   = (u8*)(ws + off);     off += align16((size_t)2 * E);
    u32*    colw   = (u32*)(ws + off);    off += align16((size_t)2 * E * 4);
    u32*    mat    = (u32*)(ws + off);    off += align16((size_t)M * 4);
    u32*    mscan  = (u32*)(ws + off);    off += align16((size_t)M * 4);
    u32*    row_ptr= (u32*)(ws + off);    off += align16((size_t)(N + 1) * 4);
    u32*    bsum   = (u32*)(ws + off);    off += align16(256 * 4);

    k_norm_hist<<<rb + nblkE, 512, 0, stream>>>(emb, x0h, ei, mat, N, E, rb, B, nblkE);
    k_scan1  <<<nb1, 256, 0, stream>>>(mat, mscan, bsum, M);
    k_scanfix<<<(M + 255) / 256, 256, 0, stream>>>(mscan, bsum, nb1, M);
    k_place  <<<nblkE, 512, 0, stream>>>(ei, w, mscan, pay, loc8, E, nblkE, B);
    k_bucket <<<B, 256, 0, stream>>>(pay, loc8, mscan, row_ptr, colw, N, E, B, nblkE);

    k_conv1<<<cvb, 256, 0, stream>>>(x0h, row_ptr, colw, x1h, N);
    k_conv2<<<cvb, 256, 0, stream>>>(x0h, x1h, row_ptr, colw, out, N);
}